// Round 4
// baseline (392.250 us; speedup 1.0000x reference)
//
#include <hip/hip_runtime.h>

// OnlineEmbedding: out[b,h,:] = table[ids[b,h], :]
// ids: [4096*200] int32 (values < 1e6), table: [1e6, 64] fp32, out: [4096*200, 64] fp32.
//
// Layout: 16 consecutive lanes per row (lane c handles the c-th float4 of the
// 256B embedding row) -> each wave-level load/store instruction touches 4
// consecutive rows = 1KB contiguous; each block-level iteration touches 16
// consecutive rows = 4KB contiguous.
//
// R4 = R1 with the compile fix: __builtin_nontemporal_* requires a native
// clang vector type, not HIP's float4 class -> use ext_vector_type(4) float.
// Same layout (16B), same dwordx4 codegen.
//
// R1 changes vs 392us baseline:
//  1. UNROLL=4 independent gathers per thread (ids batched, then 4 independent
//     table loads, then 4 stores) -> 4x memory-level parallelism per wave,
//     4x fewer waves.
//  2. Non-temporal stores for the output stream + non-temporal loads for the
//     read-once ids stream: the 256MB table *just* fits the 256MiB Infinity
//     Cache, but only if the 210MB write-once output stream doesn't evict it.
//     nt keeps L3 reserved for the table -> table reads become L3 hits instead
//     of random 256B HBM misses.

typedef float f32x4 __attribute__((ext_vector_type(4)));

#define UNROLL 4

__global__ __launch_bounds__(256) void OnlineEmbedding_gather(
    const int* __restrict__ ids,
    const f32x4* __restrict__ table,
    f32x4* __restrict__ out,
    int n_ids)
{
    const int c = threadIdx.x & 15;          // which 16B chunk of the 256B row
    const int g = threadIdx.x >> 4;          // row-group within block: 0..15
    // Block handles 16*UNROLL = 64 consecutive rows; iteration k covers rows
    // [block_base + 16k, block_base + 16k + 15] -> contiguous 4KB per iter.
    const int row0 = blockIdx.x * (16 * UNROLL) + g;

    // Phase 1: batch the id loads (independent, non-temporal: read-once stream).
    int id[UNROLL];
#pragma unroll
    for (int k = 0; k < UNROLL; ++k) {
        int r = row0 + 16 * k;
        id[k] = (r < n_ids) ? __builtin_nontemporal_load(&ids[r]) : 0;
    }

    // Phase 2: issue all table loads back-to-back (16 random 256B segments in
    // flight per wave). Cached normally -- we WANT these resident in L2/L3.
    f32x4 v[UNROLL];
#pragma unroll
    for (int k = 0; k < UNROLL; ++k) {
        v[k] = table[(size_t)id[k] * 16 + c];
    }

    // Phase 3: non-temporal stores -- write-once stream must not evict table.
#pragma unroll
    for (int k = 0; k < UNROLL; ++k) {
        int r = row0 + 16 * k;
        if (r < n_ids) {
            __builtin_nontemporal_store(v[k], &out[(size_t)r * 16 + c]);
        }
    }
}

extern "C" void kernel_launch(void* const* d_in, const int* in_sizes, int n_in,
                              void* d_out, int out_size, void* d_ws, size_t ws_size,
                              hipStream_t stream) {
    const int*   ids   = (const int*)d_in[0];
    const f32x4* table = (const f32x4*)d_in[1];
    f32x4*       out   = (f32x4*)d_out;

    int n_ids = in_sizes[0];                       // 4096*200 = 819200
    int rows_per_block = 16 * UNROLL;              // 64
    int block = 256;
    int grid  = (n_ids + rows_per_block - 1) / rows_per_block;  // 12800

    OnlineEmbedding_gather<<<grid, block, 0, stream>>>(ids, table, out, n_ids);
}